// Round 4
// baseline (291.345 us; speedup 1.0000x reference)
//
#include <hip/hip_runtime.h>

// 9x9 box filter (r=4), reflect padding, 24 planes of 2048x2048 f32.
// R4: re-read formulation, off-by-one FIXED. Schedule:
//   warmup   s=0..7 : vsum += h(row[s])
//   first    s=8    : vsum += h(row[8]); emit output row 0 (no subtract!)
//   steady   s=9..39: vsum += h(row[s]) - h(row[s-9]); emit row s-8
// The 9-ago row is re-loaded (L1/L2-warm) and its h recomputed with the
// exact same op order, so the sliding-window cancellation is bit-exact.
// No h-history in registers -> low VGPR -> high occupancy; branchless
// steady loop with 8 independent float4 loads/step -> deep MLP.

constexpr int H   = 2048;
constexpr int W   = 2048;
constexpr int R   = 4;             // radius (reference uses r=4)
constexpr int RH  = 32;            // output rows per block
constexpr int TPB = 256;           // one full row: 256 threads * 8 cols

typedef float f32x4 __attribute__((ext_vector_type(4)));

__device__ __forceinline__ int reflect_row(int r) {
  r = (r < 0) ? -r : r;
  return (r >= H) ? (2 * H - 2 - r) : r;
}

// v[i] = row[c0 - 4 + i], i = 0..15 (covers 9-windows of 8 outputs)
__device__ __forceinline__ void load16(const float* __restrict__ row, int t,
                                       int c0, float (&v)[16]) {
  if (t == 0) {
    // cols -4..-1 reflect to 4,3,2,1
    v[0] = row[4]; v[1] = row[3]; v[2] = row[2]; v[3] = row[1];
    float4 a = *(const float4*)(row + 0);
    float4 b = *(const float4*)(row + 4);
    float4 c = *(const float4*)(row + 8);
    v[4]  = a.x; v[5]  = a.y; v[6]  = a.z; v[7]  = a.w;
    v[8]  = b.x; v[9]  = b.y; v[10] = b.z; v[11] = b.w;
    v[12] = c.x; v[13] = c.y; v[14] = c.z; v[15] = c.w;
  } else if (t == TPB - 1) {
    const float* base = row + (c0 - R);   // col 2036, 16B aligned
    float4 a = *(const float4*)(base + 0);
    float4 b = *(const float4*)(base + 4);
    float4 c = *(const float4*)(base + 8);
    v[0]  = a.x; v[1]  = a.y; v[2]  = a.z; v[3]  = a.w;
    v[4]  = b.x; v[5]  = b.y; v[6]  = b.z; v[7]  = b.w;
    v[8]  = c.x; v[9]  = c.y; v[10] = c.z; v[11] = c.w;
    // cols 2048..2051 reflect to 2046,2045,2044,2043
    v[12] = row[W - 2]; v[13] = row[W - 3];
    v[14] = row[W - 4]; v[15] = row[W - 5];
  } else {
    const float* base = row + (c0 - R);   // byte addr 32t-16: 16B aligned
    float4 a = *(const float4*)(base + 0);
    float4 b = *(const float4*)(base + 4);
    float4 c = *(const float4*)(base + 8);
    float4 d = *(const float4*)(base + 12);
    v[0]  = a.x; v[1]  = a.y; v[2]  = a.z; v[3]  = a.w;
    v[4]  = b.x; v[5]  = b.y; v[6]  = b.z; v[7]  = b.w;
    v[8]  = c.x; v[9]  = c.y; v[10] = c.z; v[11] = c.w;
    v[12] = d.x; v[13] = d.y; v[14] = d.z; v[15] = d.w;
  }
}

// h[j] = sum(v[j..j+8]) — identical op order for add and subtract streams
// so the running-sum cancellation is bit-exact.
__device__ __forceinline__ void hsum9(const float (&v)[16], float (&h)[8]) {
  h[0] = ((v[0] + v[1]) + (v[2] + v[3])) +
         ((v[4] + v[5]) + (v[6] + v[7])) + v[8];
#pragma unroll
  for (int j = 1; j < 8; ++j) h[j] = h[j - 1] + v[j + 8] - v[j - 1];
}

__global__ __launch_bounds__(TPB) void BoxFilter_kernel(
    const float* __restrict__ x, float* __restrict__ out) {
  const int t     = threadIdx.x;
  const int bid   = blockIdx.x;
  const int plane = bid >> 6;        // H/RH == 64 chunks per plane
  const int chunk = bid & 63;
  const int r0    = chunk * RH;
  const float* __restrict__ px = x   + (size_t)plane * H * W;
  float*       __restrict__ po = out + (size_t)plane * H * W;
  const int c0 = t << 3;             // this thread's first output column

  const float inv81 = 1.0f / 81.0f;

  float vsum[8];
#pragma unroll
  for (int j = 0; j < 8; ++j) vsum[j] = 0.0f;

  // warmup: rows s = 0..7 (add only)
#pragma unroll
  for (int s = 0; s < 2 * R; ++s) {
    const int lr = reflect_row(r0 - R + s);
    float v[16], h[8];
    load16(px + (size_t)lr * W, t, c0, v);
    hsum9(v, h);
#pragma unroll
    for (int j = 0; j < 8; ++j) vsum[j] += h[j];
  }

  // first output step: s = 8, add row 8, emit output row r0 (no subtract)
  {
    const int lr = reflect_row(r0 - R + 2 * R);
    float v[16], h[8];
    load16(px + (size_t)lr * W, t, c0, v);
    hsum9(v, h);
#pragma unroll
    for (int j = 0; j < 8; ++j) vsum[j] += h[j];
    float* o = po + (size_t)r0 * W + c0;
    f32x4 o0 = {vsum[0] * inv81, vsum[1] * inv81,
                vsum[2] * inv81, vsum[3] * inv81};
    f32x4 o1 = {vsum[4] * inv81, vsum[5] * inv81,
                vsum[6] * inv81, vsum[7] * inv81};
    __builtin_nontemporal_store(o0, (f32x4*)(o + 0));
    __builtin_nontemporal_store(o1, (f32x4*)(o + 4));
  }

  // steady state: s = 9 .. RH+7; branchless, 8 independent float4 loads/step
#pragma unroll 4
  for (int s = 2 * R + 1; s < RH + 2 * R; ++s) {
    const int lrn = reflect_row(r0 - R + s);        // row entering window
    const int lro = reflect_row(r0 - R + s - 9);    // row leaving window
    float vn[16], vo[16], hn[8], ho[8];
    load16(px + (size_t)lrn * W, t, c0, vn);
    load16(px + (size_t)lro * W, t, c0, vo);
    hsum9(vn, hn);
    hsum9(vo, ho);
#pragma unroll
    for (int j = 0; j < 8; ++j) vsum[j] += hn[j] - ho[j];

    float* o = po + (size_t)(r0 + s - 2 * R) * W + c0;
    f32x4 o0 = {vsum[0] * inv81, vsum[1] * inv81,
                vsum[2] * inv81, vsum[3] * inv81};
    f32x4 o1 = {vsum[4] * inv81, vsum[5] * inv81,
                vsum[6] * inv81, vsum[7] * inv81};
    __builtin_nontemporal_store(o0, (f32x4*)(o + 0));
    __builtin_nontemporal_store(o1, (f32x4*)(o + 4));
  }
}

extern "C" void kernel_launch(void* const* d_in, const int* in_sizes, int n_in,
                              void* d_out, int out_size, void* d_ws, size_t ws_size,
                              hipStream_t stream) {
  const float* x   = (const float*)d_in[0];
  float*       out = (float*)d_out;
  const int planes = out_size / (H * W);        // 8*3 = 24
  dim3 grid(planes * (H / RH));                 // 24 * 64 = 1536 blocks
  dim3 block(TPB);
  hipLaunchKernelGGL(BoxFilter_kernel, grid, block, 0, stream, x, out);
}